// Round 2
// baseline (7278.156 us; speedup 1.0000x reference)
//
#include <hip/hip_runtime.h>
#include <cmath>

#define N_TOK 8192
#define DIM 1024

// ---------------- ws layout (bytes) ----------------
// 0        : int cnt[3]
// 64       : int perm[3*8192]
// 131072   : float hidden[8192*1024]   (token-indexed, stride 1024; only first pd_i valid)
// 33685504 : float pm[8192*4]          (partial max per split)
// 33816576 : float psum[8192*4]        (partial sumexp per split)
// 33947648 : float tlog[8192]          (target logit)
// total ~34 MB

__global__ __launch_bounds__(64) void k_init(int* cnt) {
  if (threadIdx.x < 3) cnt[threadIdx.x] = 0;
}

__global__ __launch_bounds__(256) void k_classify(const int* __restrict__ tgt,
                                                  int* __restrict__ cnt,
                                                  int* __restrict__ perm) {
  int n = blockIdx.x * 256 + threadIdx.x;
  if (n < N_TOK) {
    int t = tgt[n];
    int cid = (t < 10000) ? 0 : (t < 30000 ? 1 : 2);
    int slot = atomicAdd(&cnt[cid], 1);
    perm[cid * N_TOK + slot] = n;
  }
}

// hidden[token][d] = sum_k x[token][k] * p[d][k], d in [0,pd)
__global__ __launch_bounds__(256) void k_hidden(const float* __restrict__ x,
    const float* __restrict__ p0, const float* __restrict__ p1, const float* __restrict__ p2,
    const int* __restrict__ perm, const int* __restrict__ cnt,
    float* __restrict__ hidden) {
  const int cid = blockIdx.z;
  const int pd = (cid == 0) ? 1024 : (cid == 1) ? 512 : 256;
  const int dim0 = blockIdx.y * 64;
  if (dim0 >= pd) return;
  const int count = cnt[cid];
  const int tile = blockIdx.x;
  if (tile * 64 >= count) return;
  const float* p = (cid == 0) ? p0 : (cid == 1) ? p1 : p2;

  __shared__ int toks[64];
  __shared__ float xs[32][68];   // [k][row], padded
  __shared__ float ps[32][68];   // [k][dim]
  const int tid = threadIdx.x;
  if (tid < 64) {
    int idx = tile * 64 + tid;
    toks[tid] = perm[cid * N_TOK + (idx < count ? idx : 0)];
  }
  __syncthreads();
  const int ty = tid >> 4, tx = tid & 15;
  float acc[4][4] = {{0.f}};
  for (int k0 = 0; k0 < DIM; k0 += 32) {
    #pragma unroll
    for (int i = 0; i < 8; ++i) {
      int e = tid + i * 256;
      int r = e >> 5, k = e & 31;
      xs[k][r] = x[(size_t)toks[r] * DIM + k0 + k];
      ps[k][r] = p[(size_t)(dim0 + r) * DIM + k0 + k];
    }
    __syncthreads();
    #pragma unroll
    for (int k = 0; k < 32; ++k) {
      const float4 a = *(const float4*)&xs[k][ty * 4];
      const float4 b = *(const float4*)&ps[k][tx * 4];
      acc[0][0] += a.x * b.x; acc[0][1] += a.x * b.y; acc[0][2] += a.x * b.z; acc[0][3] += a.x * b.w;
      acc[1][0] += a.y * b.x; acc[1][1] += a.y * b.y; acc[1][2] += a.y * b.z; acc[1][3] += a.y * b.w;
      acc[2][0] += a.z * b.x; acc[2][1] += a.z * b.y; acc[2][2] += a.z * b.z; acc[2][3] += a.z * b.w;
      acc[3][0] += a.w * b.x; acc[3][1] += a.w * b.y; acc[3][2] += a.w * b.z; acc[3][3] += a.w * b.w;
    }
    __syncthreads();
  }
  #pragma unroll
  for (int i = 0; i < 4; ++i) {
    int idx = tile * 64 + ty * 4 + i;
    if (idx < count) {
      float* h = hidden + (size_t)toks[ty * 4 + i] * DIM + dim0 + tx * 4;
      h[0] = acc[i][0]; h[1] = acc[i][1]; h[2] = acc[i][2]; h[3] = acc[i][3];
    }
  }
}

// Per token-tile (64 tokens), sweep cluster columns in 64-wide chunks
// (strided 4-way split across blockIdx.y), maintaining running logsumexp
// per row and capturing the target logit.
__global__ __launch_bounds__(256) void k_lse(const float* __restrict__ hidden,
    const float* __restrict__ w0_, const float* __restrict__ b0_,
    const float* __restrict__ w1_, const float* __restrict__ b1_,
    const float* __restrict__ w2_, const float* __restrict__ b2_,
    const int* __restrict__ tgt,
    const int* __restrict__ perm, const int* __restrict__ cnt,
    float* __restrict__ pm, float* __restrict__ psum, float* __restrict__ tlog) {
  const int cid = blockIdx.z;
  const int pd     = (cid == 0) ? 1024  : (cid == 1) ? 512   : 256;
  const int cstart = (cid == 0) ? 0     : (cid == 1) ? 10000 : 30000;
  const int csize  = (cid == 0) ? 10000 : (cid == 1) ? 20000 : 20257;
  const float* w = (cid == 0) ? w0_ : (cid == 1) ? w1_ : w2_;
  const float* b = (cid == 0) ? b0_ : (cid == 1) ? b1_ : b2_;
  const int count = cnt[cid];
  const int tile = blockIdx.x;
  if (tile * 64 >= count) return;
  const int split = blockIdx.y;              // 0..3
  const int nchunk = (csize + 63) >> 6;

  __shared__ int toks[64];
  __shared__ int tloc[64];
  __shared__ float hs[32][68];   // [k][row]
  __shared__ float wsh[32][68];  // [k][col]
  __shared__ float lt[64][68];   // logits tile, row-major, 16B-aligned rows
  __shared__ float bsh[64];

  const int tid = threadIdx.x;
  if (tid < 64) {
    int idx = tile * 64 + tid;
    int tok = perm[cid * N_TOK + (idx < count ? idx : 0)];
    toks[tid] = tok;
    tloc[tid] = tgt[tok] - cstart;
  }
  __syncthreads();
  const int ty = tid >> 4, tx = tid & 15;
  float run_m = -1e30f, run_s = 0.0f, tlg = 0.0f;
  int found = 0;

  for (int ch = split; ch < nchunk; ch += 4) {
    const int col0 = ch * 64;
    float acc[4][4] = {{0.f}};
    for (int k0 = 0; k0 < pd; k0 += 32) {
      #pragma unroll
      for (int i = 0; i < 8; ++i) {
        int e = tid + i * 256;
        int r = e >> 5, k = e & 31;
        hs[k][r] = hidden[(size_t)toks[r] * DIM + k0 + k];
        int wr = col0 + r;
        wsh[k][r] = (wr < csize) ? w[(size_t)wr * pd + k0 + k] : 0.0f;
      }
      __syncthreads();
      #pragma unroll
      for (int k = 0; k < 32; ++k) {
        const float4 a  = *(const float4*)&hs[k][ty * 4];
        const float4 bb = *(const float4*)&wsh[k][tx * 4];
        acc[0][0] += a.x * bb.x; acc[0][1] += a.x * bb.y; acc[0][2] += a.x * bb.z; acc[0][3] += a.x * bb.w;
        acc[1][0] += a.y * bb.x; acc[1][1] += a.y * bb.y; acc[1][2] += a.y * bb.z; acc[1][3] += a.y * bb.w;
        acc[2][0] += a.z * bb.x; acc[2][1] += a.z * bb.y; acc[2][2] += a.z * bb.z; acc[2][3] += a.z * bb.w;
        acc[3][0] += a.w * bb.x; acc[3][1] += a.w * bb.y; acc[3][2] += a.w * bb.z; acc[3][3] += a.w * bb.w;
      }
      __syncthreads();
    }
    if (tid < 64) bsh[tid] = (col0 + tid < csize) ? b[col0 + tid] : 0.0f;
    __syncthreads();
    #pragma unroll
    for (int i = 0; i < 4; ++i) {
      float4 v;
      v.x = acc[i][0] + bsh[tx * 4 + 0];
      v.y = acc[i][1] + bsh[tx * 4 + 1];
      v.z = acc[i][2] + bsh[tx * 4 + 2];
      v.w = acc[i][3] + bsh[tx * 4 + 3];
      *(float4*)&lt[ty * 4 + i][tx * 4] = v;
    }
    __syncthreads();
    if (tid < 64) {
      const int r = tid;
      const int ncols = min(64, csize - col0);
      float m = run_m;
      for (int c = 0; c < ncols; ++c) m = fmaxf(m, lt[r][c]);
      float s = run_s * expf(run_m - m);
      for (int c = 0; c < ncols; ++c) s += expf(lt[r][c] - m);
      run_m = m; run_s = s;
      const int tc = tloc[r] - col0;
      if (tc >= 0 && tc < ncols) { tlg = lt[r][tc]; found = 1; }
    }
    __syncthreads();
  }

  if (tid < 64) {
    int idx = tile * 64 + tid;
    if (idx < count) {
      int tok = toks[tid];
      pm[tok * 4 + split]   = run_m;
      psum[tok * 4 + split] = run_s;
      if (found) tlog[tok] = tlg;
    }
  }
}

__global__ __launch_bounds__(256) void k_merge(const float* __restrict__ pm,
                                               const float* __restrict__ psum,
                                               const float* __restrict__ tlog,
                                               float* __restrict__ nll) {
  int n = blockIdx.x * 256 + threadIdx.x;
  if (n < N_TOK) {
    float m = pm[n * 4];
    #pragma unroll
    for (int s = 1; s < 4; ++s) m = fmaxf(m, pm[n * 4 + s]);
    float S = 0.f;
    #pragma unroll
    for (int s = 0; s < 4; ++s) S += psum[n * 4 + s] * expf(pm[n * 4 + s] - m);
    nll[n] = m + logf(S) - tlog[n];
  }
}

__global__ __launch_bounds__(256) void k_reduce(const float* __restrict__ nll,
                                                float* __restrict__ loss) {
  float s = 0.f;
  for (int i = threadIdx.x; i < N_TOK; i += 256) s += nll[i];
  #pragma unroll
  for (int off = 32; off > 0; off >>= 1) s += __shfl_down(s, off, 64);
  __shared__ float part[4];
  if ((threadIdx.x & 63) == 0) part[threadIdx.x >> 6] = s;
  __syncthreads();
  if (threadIdx.x == 0) loss[0] = part[0] + part[1] + part[2] + part[3];
}

extern "C" void kernel_launch(void* const* d_in, const int* in_sizes, int n_in,
                              void* d_out, int out_size, void* d_ws, size_t ws_size,
                              hipStream_t stream) {
  const float* x    = (const float*)d_in[0];
  const int* tgt    = (const int*)d_in[1];
  const float* p0 = (const float*)d_in[2];
  const float* w0 = (const float*)d_in[3];
  const float* b0 = (const float*)d_in[4];
  const float* p1 = (const float*)d_in[5];
  const float* w1 = (const float*)d_in[6];
  const float* b1 = (const float*)d_in[7];
  const float* p2 = (const float*)d_in[8];
  const float* w2 = (const float*)d_in[9];
  const float* b2 = (const float*)d_in[10];
  float* out = (float*)d_out;

  char* ws = (char*)d_ws;
  int* cnt      = (int*)(ws + 0);
  int* perm     = (int*)(ws + 64);
  float* hidden = (float*)(ws + 131072);
  float* pm     = (float*)(ws + 33685504);
  float* psum   = (float*)(ws + 33816576);
  float* tlog   = (float*)(ws + 33947648);

  k_init<<<dim3(1), dim3(64), 0, stream>>>(cnt);
  k_classify<<<dim3(32), dim3(256), 0, stream>>>(tgt, cnt, perm);
  k_hidden<<<dim3(128, 16, 3), dim3(256), 0, stream>>>(x, p0, p1, p2, perm, cnt, hidden);
  k_lse<<<dim3(128, 4, 3), dim3(256), 0, stream>>>(hidden, w0, b0, w1, b1, w2, b2,
                                                   tgt, perm, cnt, pm, psum, tlog);
  k_merge<<<dim3(32), dim3(256), 0, stream>>>(pm, psum, tlog, out + 1);
  k_reduce<<<dim3(1), dim3(256), 0, stream>>>(out + 1, out);
}

// Round 3
// 774.049 us; speedup vs baseline: 9.4027x; 9.4027x over previous
//
#include <hip/hip_runtime.h>
#include <cmath>

#define N_TOK 8192
#define DIM 1024

using bf16x8 = __attribute__((ext_vector_type(8))) short;
using f32x4  = __attribute__((ext_vector_type(4))) float;

__device__ __forceinline__ unsigned short f2bf(float f) {
  unsigned u = __float_as_uint(f);
  return (unsigned short)((u + 0x7fffu + ((u >> 16) & 1u)) >> 16);
}

__global__ __launch_bounds__(64) void k_init(int* cnt) {
  if (threadIdx.x < 3) cnt[threadIdx.x] = 0;
}

__global__ __launch_bounds__(256) void k_classify(const int* __restrict__ tgt,
                                                  int* __restrict__ cnt,
                                                  int* __restrict__ perm) {
  int n = blockIdx.x * 256 + threadIdx.x;
  if (n < N_TOK) {
    int t = tgt[n];
    int cid = (t < 10000) ? 0 : (t < 30000 ? 1 : 2);
    int slot = atomicAdd(&cnt[cid], 1);
    perm[cid * N_TOK + slot] = n;
  }
}

__global__ __launch_bounds__(64) void k_prefix(const int* __restrict__ cnt, int* __restrict__ hoff) {
  if (threadIdx.x == 0) {
    hoff[0] = 0;
    hoff[1] = cnt[0] * 1024;
    hoff[2] = cnt[0] * 1024 + cnt[1] * 512;
  }
}

// Convert all 3 W matrices fp32 -> bf16 into wb (concatenated).
__global__ __launch_bounds__(256) void k_wconv(const float* __restrict__ w0,
                                               const float* __restrict__ w1,
                                               const float* __restrict__ w2,
                                               unsigned short* __restrict__ wb) {
  const int n0 = 10240000, n1 = 10240000, n2 = 5185792;
  const int total4 = (n0 + n1 + n2) >> 2;
  for (int i = blockIdx.x * 256 + threadIdx.x; i < total4; i += gridDim.x * 256) {
    int e = i << 2;
    const float* src;
    if (e < n0) src = w0 + e;
    else if (e < n0 + n1) src = w1 + (e - n0);
    else src = w2 + (e - n0 - n1);
    float4 v = *(const float4*)src;
    uint2 o;
    o.x = (unsigned)f2bf(v.x) | ((unsigned)f2bf(v.y) << 16);
    o.y = (unsigned)f2bf(v.z) | ((unsigned)f2bf(v.w) << 16);
    *(uint2*)(wb + e) = o;
  }
}

// MFMA GEMM: hidden[slot][d] = sum_k x[tok][k] * p[d][k]  (bf16 out, compact per cluster)
// Block: 128 tokens x 64 dims; 4 waves each own 32 rows x 64 cols.
__global__ __launch_bounds__(256) void k_hidden(const float* __restrict__ x,
    const float* __restrict__ p0, const float* __restrict__ p1, const float* __restrict__ p2,
    const int* __restrict__ perm, const int* __restrict__ cnt, const int* __restrict__ hoffs,
    unsigned short* __restrict__ hb) {
  const int cid = blockIdx.z;
  const int pd = (cid == 0) ? 1024 : (cid == 1) ? 512 : 256;
  const int dim0 = blockIdx.y * 64;
  if (dim0 >= pd) return;
  const int count = cnt[cid];
  const int tile = blockIdx.x;
  if (tile * 128 >= count) return;
  const float* p = (cid == 0) ? p0 : (cid == 1) ? p1 : p2;
  const size_t hoff = (size_t)hoffs[cid];

  __shared__ short As[128 * 40];   // 128 rows x (32 bf16 + 8 pad) -> 80B rows
  __shared__ short Bs[64 * 40];
  __shared__ short Os[128 * 72];   // out staging, 144B rows
  __shared__ int ptoks[128];

  const int t = threadIdx.x;
  if (t < 128) {
    int idx = tile * 128 + t;
    ptoks[t] = perm[cid * N_TOK + (idx < count ? idx : count - 1)];
  }
  __syncthreads();

  const int wv = t >> 6, lane = t & 63, m = lane & 15, q = lane >> 4;
  const int arow = t >> 1, ahalf = t & 1;   // A stage: 16 floats per thread
  const int brow = t >> 2, bq = t & 3;      // B stage: 8 floats per thread
  const int atok = ptoks[arow];
  const float* asrc0 = x + (size_t)atok * DIM + ahalf * 16;
  const float* bsrc0 = p + (size_t)(dim0 + brow) * DIM + bq * 8;

  f32x4 acc[2][4];
  #pragma unroll
  for (int s = 0; s < 2; ++s)
    #pragma unroll
    for (int c = 0; c < 4; ++c) acc[s][c] = (f32x4){0.f, 0.f, 0.f, 0.f};

  for (int k0 = 0; k0 < DIM; k0 += 32) {
    __syncthreads();
    {
      const float* sA = asrc0 + k0;
      float4 v0 = *(const float4*)(sA);
      float4 v1 = *(const float4*)(sA + 4);
      float4 v2 = *(const float4*)(sA + 8);
      float4 v3 = *(const float4*)(sA + 12);
      uint4 o0, o1;
      o0.x = (unsigned)f2bf(v0.x) | ((unsigned)f2bf(v0.y) << 16);
      o0.y = (unsigned)f2bf(v0.z) | ((unsigned)f2bf(v0.w) << 16);
      o0.z = (unsigned)f2bf(v1.x) | ((unsigned)f2bf(v1.y) << 16);
      o0.w = (unsigned)f2bf(v1.z) | ((unsigned)f2bf(v1.w) << 16);
      o1.x = (unsigned)f2bf(v2.x) | ((unsigned)f2bf(v2.y) << 16);
      o1.y = (unsigned)f2bf(v2.z) | ((unsigned)f2bf(v2.w) << 16);
      o1.z = (unsigned)f2bf(v3.x) | ((unsigned)f2bf(v3.y) << 16);
      o1.w = (unsigned)f2bf(v3.z) | ((unsigned)f2bf(v3.w) << 16);
      *(uint4*)&As[arow * 40 + ahalf * 16] = o0;
      *(uint4*)&As[arow * 40 + ahalf * 16 + 8] = o1;

      const float* sB = bsrc0 + k0;
      float4 u0 = *(const float4*)(sB);
      float4 u1 = *(const float4*)(sB + 4);
      uint4 ob;
      ob.x = (unsigned)f2bf(u0.x) | ((unsigned)f2bf(u0.y) << 16);
      ob.y = (unsigned)f2bf(u0.z) | ((unsigned)f2bf(u0.w) << 16);
      ob.z = (unsigned)f2bf(u1.x) | ((unsigned)f2bf(u1.y) << 16);
      ob.w = (unsigned)f2bf(u1.z) | ((unsigned)f2bf(u1.w) << 16);
      *(uint4*)&Bs[brow * 40 + bq * 8] = ob;
    }
    __syncthreads();
    bf16x8 a0 = *(bf16x8*)&As[(wv * 32 + m) * 40 + q * 8];
    bf16x8 a1 = *(bf16x8*)&As[(wv * 32 + 16 + m) * 40 + q * 8];
    #pragma unroll
    for (int c = 0; c < 4; ++c) {
      bf16x8 bb = *(bf16x8*)&Bs[(c * 16 + m) * 40 + q * 8];
      acc[0][c] = __builtin_amdgcn_mfma_f32_16x16x32_bf16(a0, bb, acc[0][c], 0, 0, 0);
      acc[1][c] = __builtin_amdgcn_mfma_f32_16x16x32_bf16(a1, bb, acc[1][c], 0, 0, 0);
    }
  }
  __syncthreads();
  #pragma unroll
  for (int s = 0; s < 2; ++s)
    #pragma unroll
    for (int c = 0; c < 4; ++c)
      #pragma unroll
      for (int r = 0; r < 4; ++r) {
        int row = wv * 32 + s * 16 + q * 4 + r;
        int col = c * 16 + m;
        Os[row * 72 + col] = (short)f2bf(acc[s][c][r]);
      }
  __syncthreads();
  {
    int orow = t >> 1, ohalf = t & 1;
    int slot = tile * 128 + orow;
    if (slot < count) {
      uint4 d0 = *(uint4*)&Os[orow * 72 + ohalf * 32];
      uint4 d1 = *(uint4*)&Os[orow * 72 + ohalf * 32 + 8];
      unsigned short* dst = hb + hoff + (size_t)slot * pd + dim0 + ohalf * 32;
      *(uint4*)dst = d0;
      *(uint4*)(dst + 8) = d1;
    }
  }
}

// MFMA logits + exp-sum + target-logit. Block: 128 tokens x 128-col chunks
// (chunks strided across 8 splits). No max-subtraction (logits are O(1)).
__global__ __launch_bounds__(256) void k_lse(const unsigned short* __restrict__ hb,
    const unsigned short* __restrict__ wb,
    const float* __restrict__ b0_, const float* __restrict__ b1_, const float* __restrict__ b2_,
    const int* __restrict__ tgt,
    const int* __restrict__ perm, const int* __restrict__ cnt, const int* __restrict__ hoffs,
    float* __restrict__ psum, float* __restrict__ tlog) {
  const int cid = blockIdx.z;
  const int pd     = (cid == 0) ? 1024  : (cid == 1) ? 512   : 256;
  const int cstart = (cid == 0) ? 0     : (cid == 1) ? 10000 : 30000;
  const int csize  = (cid == 0) ? 10000 : (cid == 1) ? 20000 : 20257;
  const size_t woff = (cid == 0) ? 0 : (cid == 1) ? (size_t)10240000 : (size_t)20480000;
  const float* bias = (cid == 0) ? b0_ : (cid == 1) ? b1_ : b2_;
  const int count = cnt[cid];
  const int tile = blockIdx.x;
  if (tile * 128 >= count) return;
  const size_t hoff = (size_t)hoffs[cid];
  const int split = blockIdx.y;              // 0..7
  const int nchunk = (csize + 127) >> 7;

  __shared__ short As[128 * 40];
  __shared__ short Bs[128 * 40];
  __shared__ float bsh[128];
  __shared__ int ptoks[128];
  __shared__ int tlocs[128];

  const int t = threadIdx.x;
  if (t < 128) {
    int idx = tile * 128 + t;
    int tok = perm[cid * N_TOK + (idx < count ? idx : count - 1)];
    ptoks[t] = tok;
    tlocs[t] = tgt[tok] - cstart;
  }
  __syncthreads();

  const int wv = t >> 6, lane = t & 63, m = lane & 15, q = lane >> 4;
  int tl[2][4];
  #pragma unroll
  for (int s = 0; s < 2; ++s)
    #pragma unroll
    for (int r = 0; r < 4; ++r)
      tl[s][r] = tlocs[wv * 32 + s * 16 + q * 4 + r];

  const int arow = t >> 1, ahalf = t & 1;
  const int aIdx = tile * 128 + arow;
  const unsigned short* asrc0 = hb + hoff + (size_t)(aIdx < count ? aIdx : count - 1) * pd + ahalf * 16;

  float run[2][4] = {{0.f, 0.f, 0.f, 0.f}, {0.f, 0.f, 0.f, 0.f}};
  float tcap[2][4] = {{0.f, 0.f, 0.f, 0.f}, {0.f, 0.f, 0.f, 0.f}};
  int   tfnd[2][4] = {{0, 0, 0, 0}, {0, 0, 0, 0}};

  for (int ch = split; ch < nchunk; ch += 8) {
    const int col0 = ch * 128;
    __syncthreads();                         // prior epilogue bsh reads done
    if (t < 128) {
      int cg = col0 + t;
      bsh[t] = bias[cg < csize ? cg : 0];
    }
    const int bcol = col0 + arow;
    const unsigned short* bsrc0 = wb + woff + (size_t)(bcol < csize ? bcol : 0) * pd + ahalf * 16;

    f32x4 acc[2][8];
    #pragma unroll
    for (int s = 0; s < 2; ++s)
      #pragma unroll
      for (int c = 0; c < 8; ++c) acc[s][c] = (f32x4){0.f, 0.f, 0.f, 0.f};

    for (int k0 = 0; k0 < pd; k0 += 32) {
      __syncthreads();
      {
        const unsigned short* sA = asrc0 + k0;
        uint4 v0 = *(const uint4*)sA;
        uint4 v1 = *(const uint4*)(sA + 8);
        *(uint4*)&As[arow * 40 + ahalf * 16] = v0;
        *(uint4*)&As[arow * 40 + ahalf * 16 + 8] = v1;
        const unsigned short* sB = bsrc0 + k0;
        uint4 w0 = *(const uint4*)sB;
        uint4 w1 = *(const uint4*)(sB + 8);
        *(uint4*)&Bs[arow * 40 + ahalf * 16] = w0;
        *(uint4*)&Bs[arow * 40 + ahalf * 16 + 8] = w1;
      }
      __syncthreads();
      bf16x8 a0 = *(bf16x8*)&As[(wv * 32 + m) * 40 + q * 8];
      bf16x8 a1 = *(bf16x8*)&As[(wv * 32 + 16 + m) * 40 + q * 8];
      #pragma unroll
      for (int c = 0; c < 8; ++c) {
        bf16x8 bb = *(bf16x8*)&Bs[(c * 16 + m) * 40 + q * 8];
        acc[0][c] = __builtin_amdgcn_mfma_f32_16x16x32_bf16(a0, bb, acc[0][c], 0, 0, 0);
        acc[1][c] = __builtin_amdgcn_mfma_f32_16x16x32_bf16(a1, bb, acc[1][c], 0, 0, 0);
      }
    }
    // epilogue: exp-sum + target capture (bsh visible via k-loop syncs)
    #pragma unroll
    for (int c = 0; c < 8; ++c) {
      int colg = col0 + c * 16 + m;
      if (colg < csize) {
        float bv = bsh[c * 16 + m];
        #pragma unroll
        for (int s = 0; s < 2; ++s)
          #pragma unroll
          for (int r = 0; r < 4; ++r) {
            float val = acc[s][c][r] + bv;
            run[s][r] += __expf(val);
            if (tl[s][r] == colg) { tcap[s][r] = val; tfnd[s][r] = 1; }
          }
      }
    }
  }

  #pragma unroll
  for (int s = 0; s < 2; ++s)
    #pragma unroll
    for (int r = 0; r < 4; ++r) {
      float v = run[s][r];
      v += __shfl_xor(v, 1, 64);
      v += __shfl_xor(v, 2, 64);
      v += __shfl_xor(v, 4, 64);
      v += __shfl_xor(v, 8, 64);
      run[s][r] = v;
    }
  #pragma unroll
  for (int s = 0; s < 2; ++s)
    #pragma unroll
    for (int r = 0; r < 4; ++r) {
      int rowl = wv * 32 + s * 16 + q * 4 + r;
      int idx = tile * 128 + rowl;
      if (idx < count) {
        int tok = ptoks[rowl];
        if (m == 0) psum[tok * 8 + split] = run[s][r];
        if (tfnd[s][r]) tlog[tok] = tcap[s][r];
      }
    }
}

__global__ __launch_bounds__(256) void k_merge(const float* __restrict__ psum,
                                               const float* __restrict__ tlog,
                                               float* __restrict__ nll) {
  int n = blockIdx.x * 256 + threadIdx.x;
  if (n < N_TOK) {
    float s = 0.f;
    #pragma unroll
    for (int j = 0; j < 8; ++j) s += psum[n * 8 + j];
    nll[n] = logf(s) - tlog[n];
  }
}

__global__ __launch_bounds__(256) void k_reduce(const float* __restrict__ nll,
                                                float* __restrict__ loss) {
  float s = 0.f;
  for (int i = threadIdx.x; i < N_TOK; i += 256) s += nll[i];
  #pragma unroll
  for (int off = 32; off > 0; off >>= 1) s += __shfl_down(s, off, 64);
  __shared__ float part[4];
  if ((threadIdx.x & 63) == 0) part[threadIdx.x >> 6] = s;
  __syncthreads();
  if (threadIdx.x == 0) loss[0] = part[0] + part[1] + part[2] + part[3];
}

extern "C" void kernel_launch(void* const* d_in, const int* in_sizes, int n_in,
                              void* d_out, int out_size, void* d_ws, size_t ws_size,
                              hipStream_t stream) {
  const float* x  = (const float*)d_in[0];
  const int* tgt  = (const int*)d_in[1];
  const float* p0 = (const float*)d_in[2];
  const float* w0 = (const float*)d_in[3];
  const float* b0 = (const float*)d_in[4];
  const float* p1 = (const float*)d_in[5];
  const float* w1 = (const float*)d_in[6];
  const float* b1 = (const float*)d_in[7];
  const float* p2 = (const float*)d_in[8];
  const float* w2 = (const float*)d_in[9];
  const float* b2 = (const float*)d_in[10];
  float* out = (float*)d_out;

  char* ws = (char*)d_ws;
  int* cnt            = (int*)(ws + 0);
  int* hoff           = (int*)(ws + 32);
  int* perm           = (int*)(ws + 256);
  unsigned short* wb  = (unsigned short*)(ws + 131072);            // 51,331,584 B
  unsigned short* hb  = (unsigned short*)(ws + 51462656);          // <=16,777,216 B
  float* psum         = (float*)(ws + 68239872);                   // 8192*8*4
  float* tlog         = (float*)(ws + 68502016);                   // 8192*4
  // total ws usage: 68,534,784 B

  k_init<<<dim3(1), dim3(64), 0, stream>>>(cnt);
  k_classify<<<dim3(32), dim3(256), 0, stream>>>(tgt, cnt, perm);
  k_prefix<<<dim3(1), dim3(64), 0, stream>>>(cnt, hoff);
  k_wconv<<<dim3(2048), dim3(256), 0, stream>>>(w0, w1, w2, wb);
  k_hidden<<<dim3(64, 16, 3), dim3(256), 0, stream>>>(x, p0, p1, p2, perm, cnt, hoff, hb);
  k_lse<<<dim3(64, 8, 3), dim3(256), 0, stream>>>(hb, wb, b0, b1, b2, tgt, perm, cnt, hoff,
                                                  psum, tlog);
  k_merge<<<dim3(32), dim3(256), 0, stream>>>(psum, tlog, out + 1);
  k_reduce<<<dim3(1), dim3(256), 0, stream>>>(out + 1, out);
}

// Round 4
// 631.807 us; speedup vs baseline: 11.5196x; 1.2251x over previous
//
#include <hip/hip_runtime.h>
#include <cmath>

#define N_TOK 8192
#define DIM 1024

using bf16x8 = __attribute__((ext_vector_type(8))) short;
using f32x4  = __attribute__((ext_vector_type(4))) float;

__device__ __forceinline__ unsigned short f2bf(float f) {
  unsigned u = __float_as_uint(f);
  return (unsigned short)((u + 0x7fffu + ((u >> 16) & 1u)) >> 16);
}

__device__ __forceinline__ bf16x8 pack8(float4 a, float4 b) {
  bf16x8 r;
  r[0] = (short)f2bf(a.x); r[1] = (short)f2bf(a.y);
  r[2] = (short)f2bf(a.z); r[3] = (short)f2bf(a.w);
  r[4] = (short)f2bf(b.x); r[5] = (short)f2bf(b.y);
  r[6] = (short)f2bf(b.z); r[7] = (short)f2bf(b.w);
  return r;
}

// width-16 global -> LDS direct copy; LDS dest is wave-uniform base + lane*16.
__device__ __forceinline__ void gll16(const void* g, void* l) {
  __builtin_amdgcn_global_load_lds(
      (const __attribute__((address_space(1))) void*)g,
      (__attribute__((address_space(3))) void*)l, 16, 0, 0);
}

__global__ __launch_bounds__(64) void k_init(int* cnt) {
  if (threadIdx.x < 3) cnt[threadIdx.x] = 0;
}

__global__ __launch_bounds__(256) void k_classify(const int* __restrict__ tgt,
                                                  int* __restrict__ cnt,
                                                  int* __restrict__ perm) {
  int n = blockIdx.x * 256 + threadIdx.x;
  if (n < N_TOK) {
    int t = tgt[n];
    int cid = (t < 10000) ? 0 : (t < 30000 ? 1 : 2);
    int slot = atomicAdd(&cnt[cid], 1);
    perm[cid * N_TOK + slot] = n;
  }
}

__global__ __launch_bounds__(64) void k_prefix(const int* __restrict__ cnt, int* __restrict__ hoff) {
  if (threadIdx.x == 0) {
    hoff[0] = 0;
    hoff[1] = cnt[0] * 1024;
    hoff[2] = cnt[0] * 1024 + cnt[1] * 512;
  }
}

// Convert W0,W1,W2 -> wb (bf16) and P0,P1,P2 -> pb (bf16), one pass.
__global__ __launch_bounds__(256) void k_conv(
    const float* __restrict__ w0, const float* __restrict__ w1, const float* __restrict__ w2,
    const float* __restrict__ p0, const float* __restrict__ p1, const float* __restrict__ p2,
    unsigned short* __restrict__ wb, unsigned short* __restrict__ pb) {
  const int nw0 = 10240000, nw1 = 10240000, nw2 = 5185792;
  const int np0 = 1048576, np1 = 524288, np2 = 262144;
  const int nW = nw0 + nw1 + nw2;                   // 25,665,792
  const int total4 = (nW + np0 + np1 + np2) >> 2;   // 6,875,200
  for (int i = blockIdx.x * 256 + threadIdx.x; i < total4; i += gridDim.x * 256) {
    int e = i << 2;
    const float* src;
    unsigned short* dst;
    if (e < nw0) { src = w0 + e; dst = wb + e; }
    else if (e < nw0 + nw1) { src = w1 + (e - nw0); dst = wb + e; }
    else if (e < nW) { src = w2 + (e - nw0 - nw1); dst = wb + e; }
    else {
      int ep = e - nW;
      if (ep < np0) src = p0 + ep;
      else if (ep < np0 + np1) src = p1 + (ep - np0);
      else src = p2 + (ep - np0 - np1);
      dst = pb + ep;
    }
    float4 v = *(const float4*)src;
    uint2 o;
    o.x = (unsigned)f2bf(v.x) | ((unsigned)f2bf(v.y) << 16);
    o.y = (unsigned)f2bf(v.z) | ((unsigned)f2bf(v.w) << 16);
    *(uint2*)dst = o;
  }
}

// hidden[slot][d] = sum_k x[tok][k]*p[d][k]; 128 tokens x 128 dims per block.
// A = x (fp32, direct global->VGPR, inline bf16 pack, 1-step prefetch);
// B = pb (bf16) via global_load_lds into swizzled unpadded LDS.
__global__ __launch_bounds__(256, 3) void k_hidden(
    const float* __restrict__ x, const unsigned short* __restrict__ pb,
    const int* __restrict__ perm, const int* __restrict__ cnt, const int* __restrict__ hoffs,
    unsigned short* __restrict__ hb) {
  const int cid = blockIdx.z;
  const int pd = (cid == 0) ? 1024 : (cid == 1) ? 512 : 256;
  const int dim0 = blockIdx.x * 128;
  if (dim0 >= pd) return;
  const int count = cnt[cid];
  const int tile = blockIdx.y;
  if (tile * 128 >= count) return;
  const unsigned short* pbase = pb + ((cid == 0) ? 0 : (cid == 1) ? 1048576 : 1572864);
  const size_t hoff = (size_t)hoffs[cid];

  __shared__ short Bs[4096];       // 128 rows x 32 bf16, swizzled granules
  __shared__ short Os[128 * 136];  // out staging
  __shared__ int ptoks[128];

  const int t = threadIdx.x;
  if (t < 128) {
    int idx = tile * 128 + t;
    ptoks[t] = perm[cid * N_TOK + (idx < count ? idx : count - 1)];
  }
  __syncthreads();

  const int wv = t >> 6, lane = t & 63, m = lane & 15, q = lane >> 4;
  const int rB0 = wv * 32 + (lane >> 2);
  const int rB1 = rB0 + 16;
  const int qw = (lane & 3) ^ ((lane >> 3) & 3);
  const unsigned short* pB0 = pbase + (size_t)(dim0 + rB0) * DIM + qw * 8;
  const unsigned short* pB1 = pbase + (size_t)(dim0 + rB1) * DIM + qw * 8;
  short* ldsB0 = &Bs[(wv * 2 + 0) * 512];
  short* ldsB1 = &Bs[(wv * 2 + 1) * 512];
  const int swq = q ^ ((m >> 1) & 3);
  const int rdOff = m * 32 + swq * 8;

  const int tok0 = ptoks[wv * 32 + m];
  const int tok1 = ptoks[wv * 32 + 16 + m];
  const float* pA0 = x + (size_t)tok0 * DIM + q * 8;
  const float* pA1 = x + (size_t)tok1 * DIM + q * 8;

  f32x4 acc[2][8];
  #pragma unroll
  for (int s = 0; s < 2; ++s)
    #pragma unroll
    for (int c = 0; c < 8; ++c) acc[s][c] = (f32x4){0.f, 0.f, 0.f, 0.f};

  float4 n0a = *(const float4*)pA0, n0b = *(const float4*)(pA0 + 4);
  float4 n1a = *(const float4*)pA1, n1b = *(const float4*)(pA1 + 4);

  for (int k0 = 0; k0 < DIM; k0 += 32) {
    __syncthreads();
    gll16(pB0, ldsB0);
    gll16(pB1, ldsB1);
    pB0 += 32; pB1 += 32;
    bf16x8 a0 = pack8(n0a, n0b), a1 = pack8(n1a, n1b);
    if (k0 + 32 < DIM) {
      pA0 += 32; pA1 += 32;
      n0a = *(const float4*)pA0; n0b = *(const float4*)(pA0 + 4);
      n1a = *(const float4*)pA1; n1b = *(const float4*)(pA1 + 4);
    }
    __syncthreads();
    #pragma unroll
    for (int c = 0; c < 8; ++c) {
      bf16x8 bb = *(bf16x8*)&Bs[c * 512 + rdOff];
      acc[0][c] = __builtin_amdgcn_mfma_f32_16x16x32_bf16(a0, bb, acc[0][c], 0, 0, 0);
      acc[1][c] = __builtin_amdgcn_mfma_f32_16x16x32_bf16(a1, bb, acc[1][c], 0, 0, 0);
    }
  }

  // stage to Os (wave-private rows), then coalesced bf16 store
  #pragma unroll
  for (int s = 0; s < 2; ++s)
    #pragma unroll
    for (int c = 0; c < 8; ++c)
      #pragma unroll
      for (int r = 0; r < 4; ++r)
        Os[(wv * 32 + s * 16 + q * 4 + r) * 136 + c * 16 + m] = (short)f2bf(acc[s][c][r]);
  __syncthreads();
  {
    int orow = t >> 1, ohalf = t & 1;
    int slot = tile * 128 + orow;
    if (slot < count) {
      unsigned short* dst = hb + hoff + (size_t)slot * pd + dim0 + ohalf * 64;
      const short* src = &Os[orow * 136 + ohalf * 64];
      #pragma unroll
      for (int i = 0; i < 8; ++i)
        *(uint4*)(dst + i * 8) = *(const uint4*)(src + i * 8);
    }
  }
}

// logits + exp-sum + target logit. One 128-token x 128-col GEMM per block.
__global__ __launch_bounds__(256, 4) void k_lse(
    const unsigned short* __restrict__ hb, const unsigned short* __restrict__ wb,
    const float* __restrict__ b0_, const float* __restrict__ b1_, const float* __restrict__ b2_,
    const int* __restrict__ tgt, const int* __restrict__ perm,
    const int* __restrict__ cnt, const int* __restrict__ hoffs,
    float* __restrict__ psum, float* __restrict__ tlog) {
  const int cid = blockIdx.z;
  const int pd     = (cid == 0) ? 1024  : (cid == 1) ? 512   : 256;
  const int cstart = (cid == 0) ? 0     : (cid == 1) ? 10000 : 30000;
  const int csize  = (cid == 0) ? 10000 : (cid == 1) ? 20000 : 20257;
  const size_t woff = (cid == 0) ? 0 : (cid == 1) ? (size_t)10240000 : (size_t)20480000;
  const float* bias = (cid == 0) ? b0_ : (cid == 1) ? b1_ : b2_;
  const int count = cnt[cid];
  const int tile = blockIdx.y;
  if (tile * 128 >= count) return;
  const int col0 = blockIdx.x * 128;
  if (col0 >= csize) return;
  const size_t hoff = (size_t)hoffs[cid];

  __shared__ short Bs[4096];
  __shared__ int ptoks[128];
  __shared__ int tlocs[128];
  __shared__ float bsh[128];

  const int t = threadIdx.x;
  if (t < 128) {
    int idx = tile * 128 + t;
    int tok = perm[cid * N_TOK + (idx < count ? idx : count - 1)];
    ptoks[t] = tok;
    tlocs[t] = tgt[tok] - cstart;
    int cg = col0 + t;
    bsh[t] = bias[cg < csize ? cg : 0];
  }

  const int wv = t >> 6, lane = t & 63, m = lane & 15, q = lane >> 4;
  const int rB0 = wv * 32 + (lane >> 2);
  const int rB1 = rB0 + 16;
  const int qw = (lane & 3) ^ ((lane >> 3) & 3);
  const unsigned short* pB0 = wb + woff + (size_t)min(col0 + rB0, csize - 1) * pd + qw * 8;
  const unsigned short* pB1 = wb + woff + (size_t)min(col0 + rB1, csize - 1) * pd + qw * 8;
  short* ldsB0 = &Bs[(wv * 2 + 0) * 512];
  short* ldsB1 = &Bs[(wv * 2 + 1) * 512];
  const int swq = q ^ ((m >> 1) & 3);
  const int rdOff = m * 32 + swq * 8;

  int rA0 = tile * 128 + wv * 32 + m;      if (rA0 > count - 1) rA0 = count - 1;
  int rA1 = tile * 128 + wv * 32 + 16 + m; if (rA1 > count - 1) rA1 = count - 1;
  const unsigned short* pA0 = hb + hoff + (size_t)rA0 * pd + q * 8;
  const unsigned short* pA1 = hb + hoff + (size_t)rA1 * pd + q * 8;

  __syncthreads();
  int tl[2][4];
  #pragma unroll
  for (int s = 0; s < 2; ++s)
    #pragma unroll
    for (int r = 0; r < 4; ++r)
      tl[s][r] = tlocs[wv * 32 + s * 16 + q * 4 + r];

  f32x4 acc[2][8];
  #pragma unroll
  for (int s = 0; s < 2; ++s)
    #pragma unroll
    for (int c = 0; c < 8; ++c) acc[s][c] = (f32x4){0.f, 0.f, 0.f, 0.f};

  bf16x8 aN0 = *(const bf16x8*)pA0;
  bf16x8 aN1 = *(const bf16x8*)pA1;

  for (int k0 = 0; k0 < pd; k0 += 32) {
    __syncthreads();                       // readers of prev tile done
    gll16(pB0, ldsB0);
    gll16(pB1, ldsB1);
    pB0 += 32; pB1 += 32;
    bf16x8 a0 = aN0, a1 = aN1;
    if (k0 + 32 < pd) {
      pA0 += 32; pA1 += 32;
      aN0 = *(const bf16x8*)pA0;
      aN1 = *(const bf16x8*)pA1;
    }
    __syncthreads();                       // B staged (compiler drains vmcnt)
    #pragma unroll
    for (int c = 0; c < 8; ++c) {
      bf16x8 bb = *(bf16x8*)&Bs[c * 512 + rdOff];
      acc[0][c] = __builtin_amdgcn_mfma_f32_16x16x32_bf16(a0, bb, acc[0][c], 0, 0, 0);
      acc[1][c] = __builtin_amdgcn_mfma_f32_16x16x32_bf16(a1, bb, acc[1][c], 0, 0, 0);
    }
  }

  float run[2][4] = {{0.f, 0.f, 0.f, 0.f}, {0.f, 0.f, 0.f, 0.f}};
  float tcap[2][4] = {{0.f, 0.f, 0.f, 0.f}, {0.f, 0.f, 0.f, 0.f}};
  int   tfnd[2][4] = {{0, 0, 0, 0}, {0, 0, 0, 0}};
  float bc[8];
  #pragma unroll
  for (int c = 0; c < 8; ++c) bc[c] = bsh[c * 16 + m];

  #pragma unroll
  for (int c = 0; c < 8; ++c) {
    int colg = col0 + c * 16 + m;
    if (colg < csize) {
      #pragma unroll
      for (int s = 0; s < 2; ++s)
        #pragma unroll
        for (int r = 0; r < 4; ++r) {
          float val = acc[s][c][r] + bc[c];
          run[s][r] += __expf(val);
          if (tl[s][r] == colg) { tcap[s][r] = val; tfnd[s][r] = 1; }
        }
    }
  }

  #pragma unroll
  for (int s = 0; s < 2; ++s)
    #pragma unroll
    for (int r = 0; r < 4; ++r) {
      float v = run[s][r];
      v += __shfl_xor(v, 1, 64);
      v += __shfl_xor(v, 2, 64);
      v += __shfl_xor(v, 4, 64);
      v += __shfl_xor(v, 8, 64);
      int rowl = wv * 32 + s * 16 + q * 4 + r;
      int idx = tile * 128 + rowl;
      if (idx < count) {
        int tok = ptoks[rowl];
        if (m == 0) atomicAdd(&psum[tok], v);
        if (tfnd[s][r]) tlog[tok] = tcap[s][r];
      }
    }
}

__global__ __launch_bounds__(256) void k_merge(const float* __restrict__ psum,
                                               const float* __restrict__ tlog,
                                               float* __restrict__ nll) {
  int n = blockIdx.x * 256 + threadIdx.x;
  if (n < N_TOK) nll[n] = logf(psum[n]) - tlog[n];
}

__global__ __launch_bounds__(256) void k_reduce(const float* __restrict__ nll,
                                                float* __restrict__ loss) {
  float s = 0.f;
  for (int i = threadIdx.x; i < N_TOK; i += 256) s += nll[i];
  #pragma unroll
  for (int off = 32; off > 0; off >>= 1) s += __shfl_down(s, off, 64);
  __shared__ float part[4];
  if ((threadIdx.x & 63) == 0) part[threadIdx.x >> 6] = s;
  __syncthreads();
  if (threadIdx.x == 0) loss[0] = part[0] + part[1] + part[2] + part[3];
}

extern "C" void kernel_launch(void* const* d_in, const int* in_sizes, int n_in,
                              void* d_out, int out_size, void* d_ws, size_t ws_size,
                              hipStream_t stream) {
  const float* x  = (const float*)d_in[0];
  const int* tgt  = (const int*)d_in[1];
  const float* p0 = (const float*)d_in[2];
  const float* w0 = (const float*)d_in[3];
  const float* b0 = (const float*)d_in[4];
  const float* p1 = (const float*)d_in[5];
  const float* w1 = (const float*)d_in[6];
  const float* b1 = (const float*)d_in[7];
  const float* p2 = (const float*)d_in[8];
  const float* w2 = (const float*)d_in[9];
  const float* b2 = (const float*)d_in[10];
  float* out = (float*)d_out;

  char* ws = (char*)d_ws;
  int* cnt            = (int*)(ws + 0);
  int* hoff           = (int*)(ws + 64);
  int* perm           = (int*)(ws + 256);                 // 98,304 B
  unsigned short* wb  = (unsigned short*)(ws + 131072);   // 51,331,584 B
  unsigned short* pb  = (unsigned short*)(ws + 51462656); //  3,670,016 B
  unsigned short* hb  = (unsigned short*)(ws + 55132672); // 16,777,216 B
  float* psum         = (float*)(ws + 71909888);          //     32,768 B
  float* tlog         = (float*)(ws + 71942656);          //     32,768 B
  // total ws usage: 71,975,424 B

  hipMemsetAsync(psum, 0, N_TOK * sizeof(float), stream);
  k_init<<<dim3(1), dim3(64), 0, stream>>>(cnt);
  k_classify<<<dim3(32), dim3(256), 0, stream>>>(tgt, cnt, perm);
  k_prefix<<<dim3(1), dim3(64), 0, stream>>>(cnt, hoff);
  k_conv<<<dim3(4096), dim3(256), 0, stream>>>(w0, w1, w2, p0, p1, p2, wb, pb);
  k_hidden<<<dim3(8, 32, 3), dim3(256), 0, stream>>>(x, pb, perm, cnt, hoff, hb);
  k_lse<<<dim3(159, 32, 3), dim3(256), 0, stream>>>(hb, wb, b0, b1, b2, tgt, perm, cnt, hoff,
                                                    psum, tlog);
  k_merge<<<dim3(32), dim3(256), 0, stream>>>(psum, tlog, out + 1);
  k_reduce<<<dim3(1), dim3(256), 0, stream>>>(out + 1, out);
}

// Round 5
// 545.187 us; speedup vs baseline: 13.3498x; 1.1589x over previous
//
#include <hip/hip_runtime.h>
#include <cmath>

#define N_TOK 8192
#define DIM 1024

using bf16x8 = __attribute__((ext_vector_type(8))) short;
using f32x4  = __attribute__((ext_vector_type(4))) float;

__device__ __forceinline__ unsigned short f2bf(float f) {
  unsigned u = __float_as_uint(f);
  return (unsigned short)((u + 0x7fffu + ((u >> 16) & 1u)) >> 16);
}

// width-16 global->LDS DMA. Global address is per-lane; LDS dest is
// wave-uniform base + lane*16.
__device__ __forceinline__ void gll16(const void* g, void* l) {
  __builtin_amdgcn_global_load_lds(
      (const __attribute__((address_space(1))) void*)g,
      (__attribute__((address_space(3))) void*)l, 16, 0, 0);
}

// bucket tokens by cluster; one block.
__global__ __launch_bounds__(1024) void k_setup(const int* __restrict__ tgt,
                                                int* __restrict__ cnt,
                                                int* __restrict__ hoff,
                                                int* __restrict__ perm) {
  __shared__ int base[3];
  int t = threadIdx.x;
  if (t < 3) base[t] = 0;
  __syncthreads();
  for (int i = t; i < N_TOK; i += 1024) {
    int tg = tgt[i];
    int cid = (tg < 10000) ? 0 : (tg < 30000 ? 1 : 2);
    int slot = atomicAdd(&base[cid], 1);
    perm[cid * N_TOK + slot] = i;
  }
  __syncthreads();
  if (t < 3) cnt[t] = base[t];
  if (t == 0) {
    hoff[0] = 0;
    hoff[1] = base[0] * 1024;
    hoff[2] = base[0] * 1024 + base[1] * 512;
  }
}

// W0..2 -> wb (bf16), P0..2 -> pb (bf16), RNE.
__global__ __launch_bounds__(256) void k_conv(
    const float* __restrict__ w0, const float* __restrict__ w1, const float* __restrict__ w2,
    const float* __restrict__ p0, const float* __restrict__ p1, const float* __restrict__ p2,
    unsigned short* __restrict__ wb, unsigned short* __restrict__ pb) {
  const int nw0 = 10240000, nw1 = 10240000, nw2 = 5185792;
  const int np0 = 1048576, np1 = 524288, np2 = 262144;
  const int nW = nw0 + nw1 + nw2;
  const int total4 = (nW + np0 + np1 + np2) >> 2;
  for (int i = blockIdx.x * 256 + threadIdx.x; i < total4; i += gridDim.x * 256) {
    int e = i << 2;
    const float* src;
    unsigned short* dst;
    if (e < nw0) { src = w0 + e; dst = wb + e; }
    else if (e < nw0 + nw1) { src = w1 + (e - nw0); dst = wb + e; }
    else if (e < nW) { src = w2 + (e - nw0 - nw1); dst = wb + e; }
    else {
      int ep = e - nW;
      if (ep < np0) src = p0 + ep;
      else if (ep < np0 + np1) src = p1 + (ep - np0);
      else src = p2 + (ep - np0 - np1);
      dst = pb + ep;
    }
    float4 v = *(const float4*)src;
    uint2 o;
    o.x = (unsigned)f2bf(v.x) | ((unsigned)f2bf(v.y) << 16);
    o.y = (unsigned)f2bf(v.z) | ((unsigned)f2bf(v.w) << 16);
    *(uint2*)dst = o;
  }
}

// hidden: 64 tokens x 128 dims per block, BK=64.
// A = x fp32 direct+truncate-pack (prefetched); B = pb via gll16, swizzled LDS.
__global__ __launch_bounds__(256) void k_hidden(
    const float* __restrict__ x, const unsigned short* __restrict__ pb,
    const int* __restrict__ perm, const int* __restrict__ cnt, const int* __restrict__ hoffs,
    unsigned short* __restrict__ hb) {
  const int cid = blockIdx.z;
  const int pd = (cid == 0) ? 1024 : (cid == 1) ? 512 : 256;
  const int dim0 = blockIdx.x * 128;
  if (dim0 >= pd) return;
  const int count = cnt[cid];
  const int tile = blockIdx.y;
  if (tile * 64 >= count) return;
  const unsigned short* pbase = pb + ((cid == 0) ? 0 : (cid == 1) ? 1048576 : 1572864);
  const size_t hoff = (size_t)hoffs[cid];

  __shared__ short Bs[128 * 64];   // 16 KB
  __shared__ short Os[64 * 136];

  const int t = threadIdx.x, wv = t >> 6, lane = t & 63, m = lane & 15, q = lane >> 4;
  const int wr = wv >> 1, wc = wv & 1;

  // B staging: 16 instances of 8 rows x 8 granules; this wave does 4.
  const unsigned short* pB[4];
  short* ldsB[4];
  #pragma unroll
  for (int i = 0; i < 4; ++i) {
    int inst = wv * 4 + i;
    int r = inst * 8 + (lane >> 3);
    int g = (lane & 7) ^ (r & 7);
    pB[i] = pbase + (size_t)(dim0 + r) * DIM + g * 8;
    ldsB[i] = Bs + inst * 512;
  }

  // A: rows tile*64 + wr*32 + rt*16 + m
  const unsigned* pA[2];
  #pragma unroll
  for (int rt = 0; rt < 2; ++rt) {
    int idx = tile * 64 + wr * 32 + rt * 16 + m;
    int tok = perm[cid * N_TOK + min(idx, count - 1)];
    pA[rt] = (const unsigned*)(x + (size_t)tok * DIM) + q * 8;
  }

  f32x4 acc[2][4];
  #pragma unroll
  for (int rt = 0; rt < 2; ++rt)
    #pragma unroll
    for (int ct = 0; ct < 4; ++ct) acc[rt][ct] = (f32x4){0.f, 0.f, 0.f, 0.f};

  uint4 cur[2][2][2];   // [rt][h][pair-of-4]
  #pragma unroll
  for (int rt = 0; rt < 2; ++rt)
    #pragma unroll
    for (int h = 0; h < 2; ++h) {
      cur[rt][h][0] = *(const uint4*)(pA[rt] + h * 32);
      cur[rt][h][1] = *(const uint4*)(pA[rt] + h * 32 + 4);
    }

  for (int k0 = 0; k0 < DIM; k0 += 64) {
    __syncthreads();
    #pragma unroll
    for (int i = 0; i < 4; ++i) gll16(pB[i] + k0, ldsB[i]);
    __syncthreads();
    // pack current A (truncation)
    union { bf16x8 v; unsigned u[4]; } af[2][2];
    #pragma unroll
    for (int rt = 0; rt < 2; ++rt)
      #pragma unroll
      for (int h = 0; h < 2; ++h) {
        uint4 a = cur[rt][h][0], b = cur[rt][h][1];
        af[rt][h].u[0] = (a.x >> 16) | (a.y & 0xFFFF0000u);
        af[rt][h].u[1] = (a.z >> 16) | (a.w & 0xFFFF0000u);
        af[rt][h].u[2] = (b.x >> 16) | (b.y & 0xFFFF0000u);
        af[rt][h].u[3] = (b.z >> 16) | (b.w & 0xFFFF0000u);
      }
    if (k0 + 64 < DIM) {
      #pragma unroll
      for (int rt = 0; rt < 2; ++rt)
        #pragma unroll
        for (int h = 0; h < 2; ++h) {
          cur[rt][h][0] = *(const uint4*)(pA[rt] + k0 + 64 + h * 32);
          cur[rt][h][1] = *(const uint4*)(pA[rt] + k0 + 64 + h * 32 + 4);
        }
    }
    #pragma unroll
    for (int ct = 0; ct < 4; ++ct) {
      int r = wc * 64 + ct * 16 + m;
      int sw = r & 7;
      bf16x8 b0 = *(bf16x8*)&Bs[r * 64 + (q ^ sw) * 8];
      bf16x8 b1 = *(bf16x8*)&Bs[r * 64 + ((4 + q) ^ sw) * 8];
      #pragma unroll
      for (int rt = 0; rt < 2; ++rt) {
        acc[rt][ct] = __builtin_amdgcn_mfma_f32_16x16x32_bf16(af[rt][0].v, b0, acc[rt][ct], 0, 0, 0);
        acc[rt][ct] = __builtin_amdgcn_mfma_f32_16x16x32_bf16(af[rt][1].v, b1, acc[rt][ct], 0, 0, 0);
      }
    }
  }

  #pragma unroll
  for (int rt = 0; rt < 2; ++rt)
    #pragma unroll
    for (int ct = 0; ct < 4; ++ct)
      #pragma unroll
      for (int r = 0; r < 4; ++r)
        Os[(wr * 32 + rt * 16 + q * 4 + r) * 136 + wc * 64 + ct * 16 + m] =
            (short)f2bf(acc[rt][ct][r]);
  __syncthreads();
  {
    int orow = t >> 2, opart = t & 3;
    int slot = tile * 64 + orow;
    if (slot < count) {
      unsigned short* dst = hb + hoff + (size_t)slot * pd + dim0 + opart * 32;
      const short* src = &Os[orow * 136 + opart * 32];
      #pragma unroll
      for (int i = 0; i < 4; ++i)
        *(uint4*)(dst + i * 8) = *(const uint4*)(src + i * 8);
    }
  }
}

// logits + exp-sum + target logit. 128 tok x 128 col per block, BK=64,
// A and B both via gll16 into swizzled LDS; XCD-locality block remap.
__global__ __launch_bounds__(256) void k_lse(
    const unsigned short* __restrict__ hb, const unsigned short* __restrict__ wb,
    const float* __restrict__ b0_, const float* __restrict__ b1_, const float* __restrict__ b2_,
    const int* __restrict__ tgt, const int* __restrict__ perm,
    const int* __restrict__ cnt, const int* __restrict__ hoffs,
    float* __restrict__ psum, float* __restrict__ tlog) {
  const int cid = blockIdx.z;
  const int pd     = (cid == 0) ? 1024  : (cid == 1) ? 512   : 256;
  const int cstart = (cid == 0) ? 0     : (cid == 1) ? 10000 : 30000;
  const int csize  = (cid == 0) ? 10000 : (cid == 1) ? 20000 : 20257;
  const size_t woff = (cid == 0) ? 0 : (cid == 1) ? (size_t)10240000 : (size_t)20480000;
  const float* bias = (cid == 0) ? b0_ : (cid == 1) ? b1_ : b2_;
  const int count = cnt[cid];
  if (count == 0) return;
  const unsigned ntile = (unsigned)(count + 127) >> 7;
  const int nchunk = (csize + 127) >> 7;
  const int cpx = (nchunk + 7) >> 3;         // chunks per pseudo-XCD

  // XCD-locality remap: id%8 = pseudo-XCD owns contiguous chunk range,
  // all token tiles of a chunk consecutive within it.
  const unsigned d = blockIdx.x;
  const int x8 = d & 7;
  const unsigned g = d >> 3;
  const unsigned ci = g / ntile;
  if (ci >= (unsigned)cpx) return;
  const int chunk = x8 * cpx + (int)ci;
  if (chunk >= nchunk) return;
  const int tile = (int)(g - ci * ntile);
  const int col0 = chunk * 128;
  const int row0 = tile * 128;
  const size_t hoff = (size_t)hoffs[cid];

  __shared__ short As[128 * 64];   // 16 KB
  __shared__ short Bs[128 * 64];   // 16 KB
  __shared__ int ptoks[128];
  __shared__ int tlocs[128];
  __shared__ float bsh[128];

  const int t = threadIdx.x, wv = t >> 6, lane = t & 63, m = lane & 15, q = lane >> 4;
  const int wr = wv >> 1, wc = wv & 1;

  if (t < 128) {
    int idx = row0 + t;
    int tok = perm[cid * N_TOK + min(idx, count - 1)];
    ptoks[t] = tok;
    tlocs[t] = tgt[tok] - cstart;
    bsh[t] = bias[min(col0 + t, csize - 1)];
  }

  const unsigned short *pA[4], *pB[4];
  short *ldsA[4], *ldsB[4];
  #pragma unroll
  for (int i = 0; i < 4; ++i) {
    int inst = wv * 4 + i;
    int r = inst * 8 + (lane >> 3);
    int gsl = (lane & 7) ^ (r & 7);
    pA[i] = hb + hoff + (size_t)min(row0 + r, count - 1) * pd + gsl * 8;
    ldsA[i] = As + inst * 512;
    pB[i] = wb + woff + (size_t)min(col0 + r, csize - 1) * pd + gsl * 8;
    ldsB[i] = Bs + inst * 512;
  }

  f32x4 acc[4][4];
  #pragma unroll
  for (int rt = 0; rt < 4; ++rt)
    #pragma unroll
    for (int ct = 0; ct < 4; ++ct) acc[rt][ct] = (f32x4){0.f, 0.f, 0.f, 0.f};

  for (int k0 = 0; k0 < pd; k0 += 64) {
    __syncthreads();
    #pragma unroll
    for (int i = 0; i < 4; ++i) {
      gll16(pA[i] + k0, ldsA[i]);
      gll16(pB[i] + k0, ldsB[i]);
    }
    __syncthreads();
    bf16x8 af[4][2];
    #pragma unroll
    for (int rt = 0; rt < 4; ++rt) {
      int r = wr * 64 + rt * 16 + m;
      int sw = r & 7;
      af[rt][0] = *(bf16x8*)&As[r * 64 + (q ^ sw) * 8];
      af[rt][1] = *(bf16x8*)&As[r * 64 + ((4 + q) ^ sw) * 8];
    }
    #pragma unroll
    for (int ct = 0; ct < 4; ++ct) {
      int r = wc * 64 + ct * 16 + m;
      int sw = r & 7;
      bf16x8 b0 = *(bf16x8*)&Bs[r * 64 + (q ^ sw) * 8];
      bf16x8 b1 = *(bf16x8*)&Bs[r * 64 + ((4 + q) ^ sw) * 8];
      #pragma unroll
      for (int rt = 0; rt < 4; ++rt) {
        acc[rt][ct] = __builtin_amdgcn_mfma_f32_16x16x32_bf16(af[rt][0], b0, acc[rt][ct], 0, 0, 0);
        acc[rt][ct] = __builtin_amdgcn_mfma_f32_16x16x32_bf16(af[rt][1], b1, acc[rt][ct], 0, 0, 0);
      }
    }
  }

  // epilogue: exp-sum per row + target capture
  float run[4][4] = {{0.f}}, tcap[4][4] = {{0.f}};
  int tfnd[4][4] = {{0}};
  int tl[4][4];
  #pragma unroll
  for (int rt = 0; rt < 4; ++rt)
    #pragma unroll
    for (int r = 0; r < 4; ++r)
      tl[rt][r] = tlocs[wr * 64 + rt * 16 + q * 4 + r];

  #pragma unroll
  for (int ct = 0; ct < 4; ++ct) {
    int colg = col0 + wc * 64 + ct * 16 + m;
    float bv = bsh[wc * 64 + ct * 16 + m];
    bool cok = colg < csize;
    #pragma unroll
    for (int rt = 0; rt < 4; ++rt)
      #pragma unroll
      for (int r = 0; r < 4; ++r) {
        float val = acc[rt][ct][r] + bv;
        if (cok) {
          run[rt][r] += __expf(val);
          if (tl[rt][r] == colg) { tcap[rt][r] = val; tfnd[rt][r] = 1; }
        }
      }
  }

  #pragma unroll
  for (int rt = 0; rt < 4; ++rt)
    #pragma unroll
    for (int r = 0; r < 4; ++r) {
      float v = run[rt][r];
      v += __shfl_xor(v, 1, 64);
      v += __shfl_xor(v, 2, 64);
      v += __shfl_xor(v, 4, 64);
      v += __shfl_xor(v, 8, 64);
      int rowl = wr * 64 + rt * 16 + q * 4 + r;
      if (row0 + rowl < count) {
        int tok = ptoks[rowl];
        if (m == 0) atomicAdd(&psum[tok], v);
        if (tfnd[rt][r]) tlog[tok] = tcap[rt][r];
      }
    }
}

__global__ __launch_bounds__(1024) void k_final(const float* __restrict__ psum,
                                                const float* __restrict__ tlog,
                                                float* __restrict__ out) {
  __shared__ float part[16];
  int t = threadIdx.x;
  float s = 0.f;
  for (int n = t; n < N_TOK; n += 1024) {
    float v = __logf(psum[n]) - tlog[n];
    out[1 + n] = v;
    s += v;
  }
  #pragma unroll
  for (int off = 32; off > 0; off >>= 1) s += __shfl_down(s, off, 64);
  if ((t & 63) == 0) part[t >> 6] = s;
  __syncthreads();
  if (t < 64) {
    float v = (t < 16) ? part[t] : 0.f;
    #pragma unroll
    for (int off = 8; off > 0; off >>= 1) v += __shfl_down(v, off, 64);
    if (t == 0) out[0] = v;
  }
}

extern "C" void kernel_launch(void* const* d_in, const int* in_sizes, int n_in,
                              void* d_out, int out_size, void* d_ws, size_t ws_size,
                              hipStream_t stream) {
  const float* x  = (const float*)d_in[0];
  const int* tgt  = (const int*)d_in[1];
  const float* p0 = (const float*)d_in[2];
  const float* w0 = (const float*)d_in[3];
  const float* b0 = (const float*)d_in[4];
  const float* p1 = (const float*)d_in[5];
  const float* w1 = (const float*)d_in[6];
  const float* b1 = (const float*)d_in[7];
  const float* p2 = (const float*)d_in[8];
  const float* w2 = (const float*)d_in[9];
  const float* b2 = (const float*)d_in[10];
  float* out = (float*)d_out;

  char* ws = (char*)d_ws;
  int* cnt            = (int*)(ws + 0);
  int* hoff           = (int*)(ws + 64);
  int* perm           = (int*)(ws + 256);                 // 98,304 B
  unsigned short* wb  = (unsigned short*)(ws + 131072);   // 51,331,584 B
  unsigned short* pb  = (unsigned short*)(ws + 51462656); //  3,670,016 B
  unsigned short* hb  = (unsigned short*)(ws + 55132672); // 16,777,216 B
  float* psum         = (float*)(ws + 71909888);          //     32,768 B
  float* tlog         = (float*)(ws + 71942656);          //     32,768 B

  hipMemsetAsync(psum, 0, N_TOK * sizeof(float), stream);
  k_setup<<<dim3(1), dim3(1024), 0, stream>>>(tgt, cnt, hoff, perm);
  k_conv<<<dim3(4096), dim3(256), 0, stream>>>(w0, w1, w2, p0, p1, p2, wb, pb);
  k_hidden<<<dim3(8, 128, 3), dim3(256), 0, stream>>>(x, pb, perm, cnt, hoff, hb);
  k_lse<<<dim3(10240, 1, 3), dim3(256), 0, stream>>>(hb, wb, b0, b1, b2, tgt, perm, cnt, hoff,
                                                     psum, tlog);
  k_final<<<dim3(1), dim3(1024), 0, stream>>>(psum, tlog, out);
}

// Round 6
// 506.991 us; speedup vs baseline: 14.3556x; 1.0753x over previous
//
#include <hip/hip_runtime.h>
#include <cmath>

#define N_TOK 8192
#define DIM 1024

using bf16x8 = __attribute__((ext_vector_type(8))) short;
using f32x4  = __attribute__((ext_vector_type(4))) float;

__device__ __forceinline__ unsigned f2bf(float f) {
  unsigned u = __float_as_uint(f);
  return (u + 0x7fffu + ((u >> 16) & 1u)) >> 16;
}

// width-16 global->LDS DMA; LDS dest = wave-uniform base + lane*16.
__device__ __forceinline__ void gll16(const void* g, void* l) {
  __builtin_amdgcn_global_load_lds(
      (const __attribute__((address_space(1))) void*)g,
      (__attribute__((address_space(3))) void*)l, 16, 0, 0);
}

__global__ __launch_bounds__(1024) void k_setup(const int* __restrict__ tgt,
                                                int* __restrict__ cnt,
                                                int* __restrict__ hoff,
                                                int* __restrict__ perm) {
  __shared__ int base[3];
  int t = threadIdx.x;
  if (t < 3) base[t] = 0;
  __syncthreads();
  for (int i = t; i < N_TOK; i += 1024) {
    int tg = tgt[i];
    int cid = (tg < 10000) ? 0 : (tg < 30000 ? 1 : 2);
    int slot = atomicAdd(&base[cid], 1);
    perm[cid * N_TOK + slot] = i;
  }
  __syncthreads();
  if (t < 3) cnt[t] = base[t];
  if (t == 0) {
    hoff[0] = 0;
    hoff[1] = base[0] * 1024;
    hoff[2] = base[0] * 1024 + base[1] * 512;
  }
}

// Fused: z==0 -> W fp32->bf16 conversion (HBM-bound);
//        z==1..3 -> hidden GEMM for cid=z-1 (compute-bound). Co-scheduled.
__global__ __launch_bounds__(256) void k_hc(
    const float* __restrict__ x,
    const float* __restrict__ p0, const float* __restrict__ p1, const float* __restrict__ p2,
    const float* __restrict__ w0, const float* __restrict__ w1, const float* __restrict__ w2,
    const int* __restrict__ perm, const int* __restrict__ cnt, const int* __restrict__ hoffs,
    unsigned short* __restrict__ wb, unsigned short* __restrict__ hb) {
  if (blockIdx.z == 0) {
    const int nw0 = 10240000, nw1 = 10240000, nw2 = 5185792;
    const int total4 = (nw0 + nw1 + nw2) >> 2;
    for (int i = blockIdx.x * 256 + threadIdx.x; i < total4; i += 512 * 256) {
      int e = i << 2;
      const float* src;
      if (e < nw0) src = w0 + e;
      else if (e < nw0 + nw1) src = w1 + (e - nw0);
      else src = w2 + (e - nw0 - nw1);
      float4 v = *(const float4*)src;
      uint2 o;
      o.x = f2bf(v.x) | (f2bf(v.y) << 16);
      o.y = f2bf(v.z) | (f2bf(v.w) << 16);
      *(uint2*)(wb + e) = o;
    }
    return;
  }
  // ---- hidden: 128 tokens x 128 dims, BK=32, ping-pong single-barrier ----
  const int cid = blockIdx.z - 1;
  const int pd = (cid == 0) ? 1024 : (cid == 1) ? 512 : 256;
  const int count = cnt[cid];
  if (count == 0) return;
  const int nchd = pd >> 7;
  const int chunk = blockIdx.x % nchd;
  const int tile = blockIdx.x / nchd;
  if (tile * 128 >= count) return;
  const int dim0 = chunk * 128, row0 = tile * 128;
  const float* P = (cid == 0) ? p0 : (cid == 1) ? p1 : p2;
  const size_t hoff = (size_t)hoffs[cid];

  __shared__ char pool[34816];          // stage 4x8KB, aliased by Os (34816B)
  __shared__ int ptoks[128];
  short* stg = (short*)pool;            // [p*8192 + (A:0/B:4096) + ...]
  short* Os = (short*)pool;

  const int t = threadIdx.x, wv = t >> 6, lane = t & 63, m = lane & 15, q = lane >> 4;
  const int wr = wv >> 1, wc = wv & 1;

  if (t < 128) {
    int idx = row0 + t;
    ptoks[t] = perm[cid * N_TOK + min(idx, count - 1)];
  }
  __syncthreads();

  // staging slots: this thread owns slots t and t+256 of each 512-slot region
  const int s0 = t, s1 = t + 256;
  const int r0 = s0 >> 2, g0 = (s0 & 3) ^ ((r0 >> 1) & 3);
  const int r1 = s1 >> 2, g1 = (s1 & 3) ^ ((r1 >> 1) & 3);
  const uint4* srcA0 = (const uint4*)(x + (size_t)ptoks[r0] * DIM) + g0 * 2;
  const uint4* srcA1 = (const uint4*)(x + (size_t)ptoks[r1] * DIM) + g1 * 2;
  const uint4* srcB0 = (const uint4*)(P + (size_t)(dim0 + r0) * DIM) + g0 * 2;
  const uint4* srcB1 = (const uint4*)(P + (size_t)(dim0 + r1) * DIM) + g1 * 2;

  f32x4 acc[4][4];
  #pragma unroll
  for (int rt = 0; rt < 4; ++rt)
    #pragma unroll
    for (int ct = 0; ct < 4; ++ct) acc[rt][ct] = (f32x4){0.f, 0.f, 0.f, 0.f};

  const int sR = (q ^ ((m >> 1) & 3)) * 8;

  // prologue: stage k-step 0 into buf 0
  {
    uint4 a0 = srcA0[0], a1 = srcA0[1], a2 = srcA1[0], a3 = srcA1[1];
    uint4 b0 = srcB0[0], b1 = srcB0[1], b2 = srcB1[0], b3 = srcB1[1];
    uint4 o;
    o.x = (a0.x >> 16) | (a0.y & 0xFFFF0000u); o.y = (a0.z >> 16) | (a0.w & 0xFFFF0000u);
    o.z = (a1.x >> 16) | (a1.y & 0xFFFF0000u); o.w = (a1.z >> 16) | (a1.w & 0xFFFF0000u);
    *(uint4*)&stg[s0 * 8] = o;
    o.x = (a2.x >> 16) | (a2.y & 0xFFFF0000u); o.y = (a2.z >> 16) | (a2.w & 0xFFFF0000u);
    o.z = (a3.x >> 16) | (a3.y & 0xFFFF0000u); o.w = (a3.z >> 16) | (a3.w & 0xFFFF0000u);
    *(uint4*)&stg[s1 * 8] = o;
    o.x = (b0.x >> 16) | (b0.y & 0xFFFF0000u); o.y = (b0.z >> 16) | (b0.w & 0xFFFF0000u);
    o.z = (b1.x >> 16) | (b1.y & 0xFFFF0000u); o.w = (b1.z >> 16) | (b1.w & 0xFFFF0000u);
    *(uint4*)&stg[4096 + s0 * 8] = o;
    o.x = (b2.x >> 16) | (b2.y & 0xFFFF0000u); o.y = (b2.z >> 16) | (b2.w & 0xFFFF0000u);
    o.z = (b3.x >> 16) | (b3.y & 0xFFFF0000u); o.w = (b3.z >> 16) | (b3.w & 0xFFFF0000u);
    *(uint4*)&stg[4096 + s1 * 8] = o;
  }

  int p = 0;
  for (int ks = 0; ks < 32; ++ks) {
    __syncthreads();
    const bool nxt = (ks + 1) < 32;
    uint4 a0, a1, a2, a3, b0, b1, b2, b3;
    if (nxt) {
      int ko = (ks + 1) * 8;
      a0 = srcA0[ko]; a1 = srcA0[ko + 1]; a2 = srcA1[ko]; a3 = srcA1[ko + 1];
      b0 = srcB0[ko]; b1 = srcB0[ko + 1]; b2 = srcB1[ko]; b3 = srcB1[ko + 1];
    }
    short* SAp = stg + p * 8192;
    short* SBp = SAp + 4096;
    bf16x8 af[4];
    #pragma unroll
    for (int rt = 0; rt < 4; ++rt)
      af[rt] = *(bf16x8*)&SAp[(wr * 64 + rt * 16 + m) * 32 + sR];
    #pragma unroll
    for (int ct = 0; ct < 4; ++ct) {
      bf16x8 bb = *(bf16x8*)&SBp[(wc * 64 + ct * 16 + m) * 32 + sR];
      #pragma unroll
      for (int rt = 0; rt < 4; ++rt)
        acc[rt][ct] = __builtin_amdgcn_mfma_f32_16x16x32_bf16(af[rt], bb, acc[rt][ct], 0, 0, 0);
    }
    if (nxt) {
      short* DA = stg + (p ^ 1) * 8192;
      short* DB = DA + 4096;
      uint4 o;
      o.x = (a0.x >> 16) | (a0.y & 0xFFFF0000u); o.y = (a0.z >> 16) | (a0.w & 0xFFFF0000u);
      o.z = (a1.x >> 16) | (a1.y & 0xFFFF0000u); o.w = (a1.z >> 16) | (a1.w & 0xFFFF0000u);
      *(uint4*)&DA[s0 * 8] = o;
      o.x = (a2.x >> 16) | (a2.y & 0xFFFF0000u); o.y = (a2.z >> 16) | (a2.w & 0xFFFF0000u);
      o.z = (a3.x >> 16) | (a3.y & 0xFFFF0000u); o.w = (a3.z >> 16) | (a3.w & 0xFFFF0000u);
      *(uint4*)&DA[s1 * 8] = o;
      o.x = (b0.x >> 16) | (b0.y & 0xFFFF0000u); o.y = (b0.z >> 16) | (b0.w & 0xFFFF0000u);
      o.z = (b1.x >> 16) | (b1.y & 0xFFFF0000u); o.w = (b1.z >> 16) | (b1.w & 0xFFFF0000u);
      *(uint4*)&DB[s0 * 8] = o;
      o.x = (b2.x >> 16) | (b2.y & 0xFFFF0000u); o.y = (b2.z >> 16) | (b2.w & 0xFFFF0000u);
      o.z = (b3.x >> 16) | (b3.y & 0xFFFF0000u); o.w = (b3.z >> 16) | (b3.w & 0xFFFF0000u);
      *(uint4*)&DB[s1 * 8] = o;
    }
    p ^= 1;
  }

  __syncthreads();   // all MFMA LDS reads done; Os aliases stage
  #pragma unroll
  for (int rt = 0; rt < 4; ++rt)
    #pragma unroll
    for (int ct = 0; ct < 4; ++ct)
      #pragma unroll
      for (int rr = 0; rr < 4; ++rr)
        Os[(wr * 64 + rt * 16 + q * 4 + rr) * 136 + wc * 64 + ct * 16 + m] =
            (short)f2bf(acc[rt][ct][rr]);
  __syncthreads();
  {
    int orow = t >> 1, oh = t & 1;
    int slot = row0 + orow;
    if (slot < count) {
      unsigned short* dst = hb + hoff + (size_t)slot * pd + dim0 + oh * 64;
      const short* src = &Os[orow * 136 + oh * 64];
      #pragma unroll
      for (int i = 0; i < 8; ++i)
        *(uint4*)(dst + i * 8) = *(const uint4*)(src + i * 8);
    }
  }
}

// logits+exp-sum+target. 128 tok x 128 col, BK=32, gll16 ping-pong,
// single barrier per k-step, XCD-locality remap.
__global__ __launch_bounds__(256) void k_lse(
    const unsigned short* __restrict__ hb, const unsigned short* __restrict__ wb,
    const float* __restrict__ b0_, const float* __restrict__ b1_, const float* __restrict__ b2_,
    const int* __restrict__ tgt, const int* __restrict__ perm,
    const int* __restrict__ cnt, const int* __restrict__ hoffs,
    float* __restrict__ psum, float* __restrict__ tlog) {
  const int cid = blockIdx.z;
  const int pd     = (cid == 0) ? 1024  : (cid == 1) ? 512   : 256;
  const int cstart = (cid == 0) ? 0     : (cid == 1) ? 10000 : 30000;
  const int csize  = (cid == 0) ? 10000 : (cid == 1) ? 20000 : 20257;
  const size_t woff = (cid == 0) ? 0 : (cid == 1) ? (size_t)10240000 : (size_t)20480000;
  const float* bias = (cid == 0) ? b0_ : (cid == 1) ? b1_ : b2_;
  const int count = cnt[cid];
  if (count == 0) return;
  const unsigned ntile = (unsigned)(count + 127) >> 7;
  const int nchunk = (csize + 127) >> 7;
  const int cpx = (nchunk + 7) >> 3;

  const unsigned d = blockIdx.x;
  const int x8 = d & 7;
  const unsigned g = d >> 3;
  const unsigned ci = g / ntile;
  if (ci >= (unsigned)cpx) return;
  const int chunk = x8 * cpx + (int)ci;
  if (chunk >= nchunk) return;
  const int tile = (int)(g - ci * ntile);
  const int col0 = chunk * 128, row0 = tile * 128;
  const size_t hoff = (size_t)hoffs[cid];

  __shared__ short SA[2][4096];   // 128 rows x 32 k, swizzled granules
  __shared__ short SB[2][4096];
  __shared__ int ptoks[128];
  __shared__ int tlocs[128];

  const int t = threadIdx.x, wv = t >> 6, lane = t & 63, m = lane & 15, q = lane >> 4;
  const int wr = wv >> 1, wc = wv & 1;

  if (t < 128) {
    int idx = row0 + t;
    int tok = perm[cid * N_TOK + min(idx, count - 1)];
    ptoks[t] = tok;
    tlocs[t] = tgt[tok] - cstart;
  }

  // DMA staging: 8 A-instances + 8 B-instances of 16 rows x 32 k; wave owns 2+2.
  const int sub = lane >> 2;
  const int gsw = (lane & 3) ^ ((sub >> 1) & 3);
  const unsigned short *pA[2], *pB[2];
  short *lA[2][2], *lB[2][2];
  #pragma unroll
  for (int i = 0; i < 2; ++i) {
    int ia = wv * 2 + i;
    int ra = ia * 16 + sub;
    pA[i] = hb + hoff + (size_t)min(row0 + ra, count - 1) * pd + gsw * 8;
    pB[i] = wb + woff + (size_t)min(col0 + ra, csize - 1) * pd + gsw * 8;
    #pragma unroll
    for (int pp = 0; pp < 2; ++pp) {
      lA[i][pp] = &SA[pp][ia * 512];
      lB[i][pp] = &SB[pp][ia * 512];
    }
  }

  float bc[4];
  #pragma unroll
  for (int ct = 0; ct < 4; ++ct)
    bc[ct] = bias[min(col0 + wc * 64 + ct * 16 + m, csize - 1)];

  f32x4 acc[4][4];
  #pragma unroll
  for (int rt = 0; rt < 4; ++rt)
    #pragma unroll
    for (int ct = 0; ct < 4; ++ct) acc[rt][ct] = (f32x4){0.f, 0.f, 0.f, 0.f};

  const int sR = (q ^ ((m >> 1) & 3)) * 8;
  const int nk = pd >> 5;

  #pragma unroll
  for (int i = 0; i < 2; ++i) { gll16(pA[i], lA[i][0]); gll16(pB[i], lB[i][0]); }

  int p = 0;
  for (int ks = 0; ks < nk; ++ks) {
    __syncthreads();                       // buf p ready; prev reads done
    if (ks + 1 < nk) {
      int ko = (ks + 1) * 32;
      #pragma unroll
      for (int i = 0; i < 2; ++i) {
        gll16(pA[i] + ko, lA[i][p ^ 1]);
        gll16(pB[i] + ko, lB[i][p ^ 1]);
      }
    }
    bf16x8 af[4];
    #pragma unroll
    for (int rt = 0; rt < 4; ++rt)
      af[rt] = *(bf16x8*)&SA[p][(wr * 64 + rt * 16 + m) * 32 + sR];
    #pragma unroll
    for (int ct = 0; ct < 4; ++ct) {
      bf16x8 bb = *(bf16x8*)&SB[p][(wc * 64 + ct * 16 + m) * 32 + sR];
      #pragma unroll
      for (int rt = 0; rt < 4; ++rt)
        acc[rt][ct] = __builtin_amdgcn_mfma_f32_16x16x32_bf16(af[rt], bb, acc[rt][ct], 0, 0, 0);
    }
    p ^= 1;
  }

  float run[4][4] = {{0.f}}, tcap[4][4] = {{0.f}};
  int tfnd[4][4] = {{0}};
  int tl[4][4];
  #pragma unroll
  for (int rt = 0; rt < 4; ++rt)
    #pragma unroll
    for (int rr = 0; rr < 4; ++rr)
      tl[rt][rr] = tlocs[wr * 64 + rt * 16 + q * 4 + rr];

  #pragma unroll
  for (int ct = 0; ct < 4; ++ct) {
    int colg = col0 + wc * 64 + ct * 16 + m;
    bool cok = colg < csize;
    #pragma unroll
    for (int rt = 0; rt < 4; ++rt)
      #pragma unroll
      for (int rr = 0; rr < 4; ++rr) {
        float val = acc[rt][ct][rr] + bc[ct];
        if (cok) {
          run[rt][rr] += __expf(val);
          if (tl[rt][rr] == colg) { tcap[rt][rr] = val; tfnd[rt][rr] = 1; }
        }
      }
  }

  #pragma unroll
  for (int rt = 0; rt < 4; ++rt)
    #pragma unroll
    for (int rr = 0; rr < 4; ++rr) {
      float v = run[rt][rr];
      v += __shfl_xor(v, 1, 64);
      v += __shfl_xor(v, 2, 64);
      v += __shfl_xor(v, 4, 64);
      v += __shfl_xor(v, 8, 64);
      int rowl = wr * 64 + rt * 16 + q * 4 + rr;
      if (row0 + rowl < count) {
        int tok = ptoks[rowl];
        if (m == 0) atomicAdd(&psum[tok], v);
        if (tfnd[rt][rr]) tlog[tok] = tcap[rt][rr];
      }
    }
}

__global__ __launch_bounds__(1024) void k_final(const float* __restrict__ psum,
                                                const float* __restrict__ tlog,
                                                float* __restrict__ out) {
  __shared__ float part[16];
  int t = threadIdx.x;
  float s = 0.f;
  for (int n = t; n < N_TOK; n += 1024) {
    float v = __logf(psum[n]) - tlog[n];
    out[1 + n] = v;
    s += v;
  }
  #pragma unroll
  for (int off = 32; off > 0; off >>= 1) s += __shfl_down(s, off, 64);
  if ((t & 63) == 0) part[t >> 6] = s;
  __syncthreads();
  if (t < 64) {
    float v = (t < 16) ? part[t] : 0.f;
    #pragma unroll
    for (int off = 8; off > 0; off >>= 1) v += __shfl_down(v, off, 64);
    if (t == 0) out[0] = v;
  }
}

extern "C" void kernel_launch(void* const* d_in, const int* in_sizes, int n_in,
                              void* d_out, int out_size, void* d_ws, size_t ws_size,
                              hipStream_t stream) {
  const float* x  = (const float*)d_in[0];
  const int* tgt  = (const int*)d_in[1];
  const float* p0 = (const float*)d_in[2];
  const float* w0 = (const float*)d_in[3];
  const float* b0 = (const float*)d_in[4];
  const float* p1 = (const float*)d_in[5];
  const float* w1 = (const float*)d_in[6];
  const float* b1 = (const float*)d_in[7];
  const float* p2 = (const float*)d_in[8];
  const float* w2 = (const float*)d_in[9];
  const float* b2 = (const float*)d_in[10];
  float* out = (float*)d_out;

  char* ws = (char*)d_ws;
  int* cnt            = (int*)(ws + 0);
  int* hoff           = (int*)(ws + 64);
  int* perm           = (int*)(ws + 256);                 // 98,304 B
  unsigned short* wb  = (unsigned short*)(ws + 131072);   // 51,331,584 B
  unsigned short* hb  = (unsigned short*)(ws + 51462656); // 16,777,216 B
  float* psum         = (float*)(ws + 68239872);          // 32,768 B
  float* tlog         = (float*)(ws + 68272640);          // 32,768 B

  hipMemsetAsync(psum, 0, N_TOK * sizeof(float), stream);
  k_setup<<<dim3(1), dim3(1024), 0, stream>>>(tgt, cnt, hoff, perm);
  k_hc<<<dim3(512, 1, 4), dim3(256), 0, stream>>>(x, p0, p1, p2, w0, w1, w2,
                                                  perm, cnt, hoff, wb, hb);
  k_lse<<<dim3(10240, 1, 3), dim3(256), 0, stream>>>(hb, wb, b0, b1, b2, tgt, perm, cnt, hoff,
                                                     psum, tlog);
  k_final<<<dim3(1), dim3(1024), 0, stream>>>(psum, tlog, out);
}